// Round 1
// baseline (3189.861 us; speedup 1.0000x reference)
//
#include <hip/hip_runtime.h>
#include <math.h>

#define N_NODES 100000
#define N_EDGES 1600000
#define DIM 64

// ex = exp(sigmoid(as+ad)); identical helper used in pass1 and pass2 so the
// recomputed value in pass2 bit-matches pass1's denominator contributions.
__device__ __forceinline__ float edge_ex(float as, float ad) {
    float x = as + ad;
    float sg = 1.0f / (1.0f + __expf(-x));
    return __expf(sg);
}

// K1: per-node attention projections. One wave per node, lane d owns dim d.
__global__ __launch_bounds__(256) void att_kernel(const float* __restrict__ q,
                                                  const float* __restrict__ W_att,
                                                  float* __restrict__ att_src,
                                                  float* __restrict__ att_dst) {
    int wave = (blockIdx.x * blockDim.x + threadIdx.x) >> 6;
    int lane = threadIdx.x & 63;
    if (wave >= N_NODES) return;
    float qv = q[wave * DIM + lane];
    float ps = qv * W_att[lane];
    float pd = qv * W_att[DIM + lane];
    #pragma unroll
    for (int off = 32; off >= 1; off >>= 1) {
        ps += __shfl_xor(ps, off);
        pd += __shfl_xor(pd, off);
    }
    if (lane == 0) {
        att_src[wave] = ps;
        att_dst[wave] = pd;
    }
}

// K2: pass1 — one thread per edge (both edge types in one grid).
// Accumulates softmax denominator per dst node.
__global__ __launch_bounds__(256) void pass1_kernel(const int* __restrict__ src1, const int* __restrict__ dst1,
                                                    const int* __restrict__ src2, const int* __restrict__ dst2,
                                                    const float* __restrict__ att_src, const float* __restrict__ att_dst,
                                                    float* __restrict__ denom1, float* __restrict__ denom2) {
    int idx = blockIdx.x * blockDim.x + threadIdx.x;
    if (idx >= 2 * N_EDGES) return;
    const int* src; const int* dst; float* denom; int e;
    if (idx < N_EDGES) { src = src1; dst = dst1; denom = denom1; e = idx; }
    else               { src = src2; dst = dst2; denom = denom2; e = idx - N_EDGES; }
    int s = src[e], d = dst[e];
    float ex = edge_ex(att_src[s], att_dst[d]);
    atomicAdd(denom + d, ex);
}

// K3: pass2 — 16 threads per edge, each thread owns a float4 chunk of the row.
// a = ex / denom[dst]; S[dst] += a * q[src]. S lives in d_out's 2nd half.
__global__ __launch_bounds__(256) void pass2_kernel(const float* __restrict__ q,
                                                    const int* __restrict__ src1, const int* __restrict__ dst1,
                                                    const int* __restrict__ src2, const int* __restrict__ dst2,
                                                    const float* __restrict__ att_src, const float* __restrict__ att_dst,
                                                    const float* __restrict__ denom1, const float* __restrict__ denom2,
                                                    float* __restrict__ S) {
    int gid = blockIdx.x * blockDim.x + threadIdx.x;
    int eidx = gid >> 4;
    int part = gid & 15;
    if (eidx >= 2 * N_EDGES) return;
    const int* src; const int* dst; const float* denom; int e;
    if (eidx < N_EDGES) { src = src1; dst = dst1; denom = denom1; e = eidx; }
    else                { src = src2; dst = dst2; denom = denom2; e = eidx - N_EDGES; }
    int s = src[e], d = dst[e];
    float ex = edge_ex(att_src[s], att_dst[d]);
    float a = ex / fmaxf(denom[d], 1e-12f);
    const float4 qv = *reinterpret_cast<const float4*>(q + (size_t)s * DIM + part * 4);
    float* outp = S + (size_t)d * DIM + part * 4;
    atomicAdd(outp + 0, a * qv.x);
    atomicAdd(outp + 1, a * qv.y);
    atomicAdd(outp + 2, a * qv.z);
    atomicAdd(outp + 3, a * qv.w);
}

// K4: per-node epilogue. wave per node; W_upd, W_V staged in padded LDS.
// q_new = (2q+S) @ W_upd.T ; OV = S @ W_V.T + (f1+f2)*b_V (written over S).
__global__ __launch_bounds__(256) void final_kernel(const float* __restrict__ q,
                                                    const float* __restrict__ W_upd,
                                                    const float* __restrict__ W_V,
                                                    const float* __restrict__ b_V,
                                                    const float* __restrict__ denom1,
                                                    const float* __restrict__ denom2,
                                                    float* __restrict__ q_new,
                                                    float* S_and_OV /* no restrict: read+write same buffer */) {
    __shared__ float wu[64][65];
    __shared__ float wv[64][65];
    for (int i = threadIdx.x; i < 64 * 64; i += 256) {
        int r = i >> 6, c = i & 63;
        wu[r][c] = W_upd[i];
        wv[r][c] = W_V[i];
    }
    __syncthreads();
    int lane = threadIdx.x & 63;
    int n = blockIdx.x * 4 + (threadIdx.x >> 6);
    if (n >= N_NODES) return;
    float qv = q[n * DIM + lane];
    float sv = S_and_OV[(size_t)n * DIM + lane];
    float u = 2.0f * qv + sv;
    float acc_u = 0.f, acc_v = 0.f;
    #pragma unroll
    for (int dd = 0; dd < 64; ++dd) {
        float ud = __shfl(u, dd);
        float sd = __shfl(sv, dd);
        acc_u += ud * wu[lane][dd];  // bank (lane+dd)%32: conflict-free
        acc_v += sd * wv[lane][dd];
    }
    float f = ((denom1[n] > 0.f) ? 1.f : 0.f) + ((denom2[n] > 0.f) ? 1.f : 0.f);
    acc_v += f * b_V[lane];
    q_new[n * DIM + lane] = acc_u;
    S_and_OV[(size_t)n * DIM + lane] = acc_v;
}

extern "C" void kernel_launch(void* const* d_in, const int* in_sizes, int n_in,
                              void* d_out, int out_size, void* d_ws, size_t ws_size,
                              hipStream_t stream) {
    const float* q     = (const float*)d_in[0];
    const float* W_att = (const float*)d_in[1];
    const float* W_upd = (const float*)d_in[2];
    const float* W_V   = (const float*)d_in[3];
    const float* b_V   = (const float*)d_in[4];
    const int*   src1  = (const int*)d_in[5];
    const int*   dst1  = (const int*)d_in[6];
    const int*   src2  = (const int*)d_in[7];
    const int*   dst2  = (const int*)d_in[8];

    float* out   = (float*)d_out;
    float* q_new = out;                              // [N,64]
    float* S     = out + (size_t)N_NODES * DIM;      // [N,64]: accum S, then OV in-place

    float* denom1  = (float*)d_ws;                   // [N]
    float* denom2  = denom1 + N_NODES;               // [N]
    float* att_src = denom2 + N_NODES;               // [N]
    float* att_dst = att_src + N_NODES;              // [N]

    // ws/out are poisoned 0xAA before every timed call — zero the accumulators.
    hipMemsetAsync(denom1, 0, 2 * (size_t)N_NODES * sizeof(float), stream);
    hipMemsetAsync(S, 0, (size_t)N_NODES * DIM * sizeof(float), stream);

    att_kernel<<<N_NODES / 4, 256, 0, stream>>>(q, W_att, att_src, att_dst);
    pass1_kernel<<<(2 * N_EDGES + 255) / 256, 256, 0, stream>>>(
        src1, dst1, src2, dst2, att_src, att_dst, denom1, denom2);
    pass2_kernel<<<((2 * N_EDGES) * 16 + 255) / 256, 256, 0, stream>>>(
        q, src1, dst1, src2, dst2, att_src, att_dst, denom1, denom2, S);
    final_kernel<<<(N_NODES + 3) / 4, 256, 0, stream>>>(
        q, W_upd, W_V, b_V, denom1, denom2, q_new, S);
}

// Round 3
// 658.629 us; speedup vs baseline: 4.8432x; 4.8432x over previous
//
#include <hip/hip_runtime.h>
#include <math.h>

#define N_NODES 100000
#define N_EDGES 1600000
#define TWO_E   (2 * N_EDGES)
#define DIM 64
#define SCAN_BLOCKS 98  // ceil(100000/1024)

// ex = exp(sigmoid(as+ad)) — same formula everywhere so denom contributions
// bit-match the per-edge numerators.
__device__ __forceinline__ float edge_ex(float as, float ad) {
    float x = as + ad;
    float sg = 1.0f / (1.0f + __expf(-x));
    return __expf(sg);
}

// K1: per-node attention projections. One wave per node, lane d owns dim d.
__global__ __launch_bounds__(256) void att_kernel(const float* __restrict__ q,
                                                  const float* __restrict__ W_att,
                                                  float* __restrict__ att_src,
                                                  float* __restrict__ att_dst) {
    int wave = (blockIdx.x * blockDim.x + threadIdx.x) >> 6;
    int lane = threadIdx.x & 63;
    if (wave >= N_NODES) return;
    float qv = q[wave * DIM + lane];
    float ps = qv * W_att[lane];
    float pd = qv * W_att[DIM + lane];
    #pragma unroll
    for (int off = 32; off >= 1; off >>= 1) {
        ps += __shfl_xor(ps, off);
        pd += __shfl_xor(pd, off);
    }
    if (lane == 0) {
        att_src[wave] = ps;
        att_dst[wave] = pd;
    }
}

// K2: histogram by dst over both edge types; returned old count = rank in bucket.
__global__ __launch_bounds__(256) void hist_kernel(const int* __restrict__ dst1,
                                                   const int* __restrict__ dst2,
                                                   int* __restrict__ count,
                                                   int* __restrict__ rank) {
    int idx = blockIdx.x * blockDim.x + threadIdx.x;
    if (idx >= TWO_E) return;
    int d = (idx < N_EDGES) ? dst1[idx] : dst2[idx - N_EDGES];
    rank[idx] = atomicAdd(count + d, 1);
}

// K3a: per-block exclusive scan of count -> offsets (block-local), block sums.
__global__ __launch_bounds__(1024) void scan1_kernel(const int* __restrict__ count,
                                                     int* __restrict__ offsets,
                                                     int* __restrict__ bsum) {
    __shared__ int wtot[16];
    int i = blockIdx.x * 1024 + threadIdx.x;
    int v = (i < N_NODES) ? count[i] : 0;
    int lane = threadIdx.x & 63, wid = threadIdx.x >> 6;
    int x = v;
    #pragma unroll
    for (int off = 1; off <= 32; off <<= 1) {
        int y = __shfl_up(x, off);
        if (lane >= off) x += y;
    }
    if (lane == 63) wtot[wid] = x;
    __syncthreads();
    if (threadIdx.x < 16) {
        int t = wtot[threadIdx.x];
        #pragma unroll
        for (int off = 1; off <= 8; off <<= 1) {
            int y = __shfl_up(t, off);
            if (threadIdx.x >= off) t += y;
        }
        wtot[threadIdx.x] = t;  // inclusive scan of wave totals
    }
    __syncthreads();
    int woff = (wid == 0) ? 0 : wtot[wid - 1];
    if (i < N_NODES) offsets[i] = woff + x - v;  // exclusive within block
    if (threadIdx.x == 0) bsum[blockIdx.x] = wtot[15];
}

// K3b: scan the 98 block sums (tiny, single block).
__global__ __launch_bounds__(128) void scan2_kernel(const int* __restrict__ bsum,
                                                    int* __restrict__ boff) {
    __shared__ int s[SCAN_BLOCKS];
    if (threadIdx.x < SCAN_BLOCKS) s[threadIdx.x] = bsum[threadIdx.x];
    __syncthreads();
    if (threadIdx.x == 0) {
        int run = 0;
        for (int b = 0; b < SCAN_BLOCKS; ++b) { int t = s[b]; s[b] = run; run += t; }
    }
    __syncthreads();
    if (threadIdx.x < SCAN_BLOCKS) boff[threadIdx.x] = s[threadIdx.x];
}

// K3c: add block offsets; write the sentinel.
__global__ __launch_bounds__(1024) void scan3_kernel(int* __restrict__ offsets,
                                                     const int* __restrict__ boff) {
    int i = blockIdx.x * 1024 + threadIdx.x;
    if (i < N_NODES) offsets[i] += boff[blockIdx.x];
    if (i == N_NODES - 1) offsets[N_NODES] = TWO_E;
}

// K4: scatter edge records into CSR buckets — NO atomics (pos = offset + rank).
// Record: {src | type<<31, ex as bits}.
__global__ __launch_bounds__(256) void scatter_kernel(const int* __restrict__ src1, const int* __restrict__ dst1,
                                                      const int* __restrict__ src2, const int* __restrict__ dst2,
                                                      const float* __restrict__ att_src, const float* __restrict__ att_dst,
                                                      const int* __restrict__ offsets, const int* __restrict__ rank,
                                                      uint2* __restrict__ recs) {
    int idx = blockIdx.x * blockDim.x + threadIdx.x;
    if (idx >= TWO_E) return;
    int s, d; unsigned tb;
    if (idx < N_EDGES) { s = src1[idx]; d = dst1[idx]; tb = 0u; }
    else               { s = src2[idx - N_EDGES]; d = dst2[idx - N_EDGES]; tb = 0x80000000u; }
    float ex = edge_ex(att_src[s], att_dst[d]);
    int pos = offsets[d] + rank[idx];
    recs[pos] = make_uint2((unsigned)s | tb, __float_as_uint(ex));
}

// K5: gather-reduce per node. 16 threads/node, each owns a float4 chunk.
// Sweep 1: per-type denominators (in-register, shfl reduce).
// Sweep 2: S[n] += (ex/denom) * q[src], one plain float4 store at the end.
__global__ __launch_bounds__(256) void gather_kernel(const float* __restrict__ q,
                                                     const int* __restrict__ offsets,
                                                     const uint2* __restrict__ recs,
                                                     float* __restrict__ S,
                                                     float* __restrict__ fbuf) {
    int node = blockIdx.x * 16 + (threadIdx.x >> 4);
    int t = threadIdx.x & 15;
    if (node >= N_NODES) return;
    int beg = offsets[node], end = offsets[node + 1];
    float d1 = 0.f, d2 = 0.f;
    for (int i = beg + t; i < end; i += 16) {
        uint2 r = recs[i];
        float ex = __uint_as_float(r.y);
        if ((int)r.x < 0) d2 += ex; else d1 += ex;
    }
    #pragma unroll
    for (int off = 8; off >= 1; off >>= 1) {
        d1 += __shfl_xor(d1, off);
        d2 += __shfl_xor(d2, off);
    }
    float inv1 = (d1 > 0.f) ? (1.0f / d1) : 0.f;
    float inv2 = (d2 > 0.f) ? (1.0f / d2) : 0.f;
    if (t == 0) fbuf[node] = ((d1 > 0.f) ? 1.f : 0.f) + ((d2 > 0.f) ? 1.f : 0.f);

    float4 acc = make_float4(0.f, 0.f, 0.f, 0.f);
    const float* qb = q + t * 4;
    int i = beg;
    for (; i + 1 < end; i += 2) {  // unroll x2 for memory-level parallelism
        uint2 r0 = recs[i], r1 = recs[i + 1];
        int s0 = r0.x & 0x7fffffff, s1 = r1.x & 0x7fffffff;
        float a0 = __uint_as_float(r0.y) * (((int)r0.x < 0) ? inv2 : inv1);
        float a1 = __uint_as_float(r1.y) * (((int)r1.x < 0) ? inv2 : inv1);
        const float4 q0 = *reinterpret_cast<const float4*>(qb + (size_t)s0 * DIM);
        const float4 q1 = *reinterpret_cast<const float4*>(qb + (size_t)s1 * DIM);
        acc.x += a0 * q0.x; acc.y += a0 * q0.y; acc.z += a0 * q0.z; acc.w += a0 * q0.w;
        acc.x += a1 * q1.x; acc.y += a1 * q1.y; acc.z += a1 * q1.z; acc.w += a1 * q1.w;
    }
    if (i < end) {
        uint2 r = recs[i];
        int s = r.x & 0x7fffffff;
        float a = __uint_as_float(r.y) * (((int)r.x < 0) ? inv2 : inv1);
        const float4 qv = *reinterpret_cast<const float4*>(qb + (size_t)s * DIM);
        acc.x += a * qv.x; acc.y += a * qv.y; acc.z += a * qv.z; acc.w += a * qv.w;
    }
    *reinterpret_cast<float4*>(S + (size_t)node * DIM + t * 4) = acc;
}

// K6: per-node epilogue. q_new = (2q+S) @ W_upd.T ; OV = S @ W_V.T + f*b_V.
__global__ __launch_bounds__(256) void final_kernel(const float* __restrict__ q,
                                                    const float* __restrict__ W_upd,
                                                    const float* __restrict__ W_V,
                                                    const float* __restrict__ b_V,
                                                    const float* __restrict__ fbuf,
                                                    float* __restrict__ q_new,
                                                    float* S_and_OV) {
    __shared__ float wu[64][65];
    __shared__ float wv[64][65];
    for (int i = threadIdx.x; i < 64 * 64; i += 256) {
        int r = i >> 6, c = i & 63;
        wu[r][c] = W_upd[i];
        wv[r][c] = W_V[i];
    }
    __syncthreads();
    int lane = threadIdx.x & 63;
    int n = blockIdx.x * 4 + (threadIdx.x >> 6);
    if (n >= N_NODES) return;
    float qv = q[n * DIM + lane];
    float sv = S_and_OV[(size_t)n * DIM + lane];
    float u = 2.0f * qv + sv;
    float acc_u = 0.f, acc_v = 0.f;
    #pragma unroll
    for (int dd = 0; dd < 64; ++dd) {
        float ud = __shfl(u, dd);
        float sd = __shfl(sv, dd);
        acc_u += ud * wu[lane][dd];  // bank (lane+dd)%32: conflict-free
        acc_v += sd * wv[lane][dd];
    }
    acc_v += fbuf[n] * b_V[lane];
    q_new[n * DIM + lane] = acc_u;
    S_and_OV[(size_t)n * DIM + lane] = acc_v;
}

extern "C" void kernel_launch(void* const* d_in, const int* in_sizes, int n_in,
                              void* d_out, int out_size, void* d_ws, size_t ws_size,
                              hipStream_t stream) {
    const float* q     = (const float*)d_in[0];
    const float* W_att = (const float*)d_in[1];
    const float* W_upd = (const float*)d_in[2];
    const float* W_V   = (const float*)d_in[3];
    const float* b_V   = (const float*)d_in[4];
    const int*   src1  = (const int*)d_in[5];
    const int*   dst1  = (const int*)d_in[6];
    const int*   src2  = (const int*)d_in[7];
    const int*   dst2  = (const int*)d_in[8];

    float* out   = (float*)d_out;
    float* q_new = out;                              // [N,64] final; holds recs until then
    float* S     = out + (size_t)N_NODES * DIM;      // [N,64]: S, then OV in-place
    uint2* recs  = (uint2*)q_new;                    // 2E * 8B == N*DIM*4B exactly

    float* att_src = (float*)d_ws;                   // N
    float* att_dst = att_src + N_NODES;              // N
    float* fbuf    = att_dst + N_NODES;              // N
    int*   count   = (int*)(fbuf + N_NODES);         // N
    int*   offsets = count + N_NODES;                // N+1
    int*   bsum    = offsets + N_NODES + 1;          // 128
    int*   boff    = bsum + 128;                     // 128
    int*   rank    = boff + 128;                     // 2E

    hipMemsetAsync(count, 0, (size_t)N_NODES * sizeof(int), stream);

    att_kernel<<<N_NODES / 4, 256, 0, stream>>>(q, W_att, att_src, att_dst);
    hist_kernel<<<(TWO_E + 255) / 256, 256, 0, stream>>>(dst1, dst2, count, rank);
    scan1_kernel<<<SCAN_BLOCKS, 1024, 0, stream>>>(count, offsets, bsum);
    scan2_kernel<<<1, 128, 0, stream>>>(bsum, boff);
    scan3_kernel<<<SCAN_BLOCKS, 1024, 0, stream>>>(offsets, boff);
    scatter_kernel<<<(TWO_E + 255) / 256, 256, 0, stream>>>(
        src1, dst1, src2, dst2, att_src, att_dst, offsets, rank, recs);
    gather_kernel<<<(N_NODES + 15) / 16, 256, 0, stream>>>(q, offsets, recs, S, fbuf);
    final_kernel<<<(N_NODES + 3) / 4, 256, 0, stream>>>(
        q, W_upd, W_V, b_V, fbuf, q_new, S);
}

// Round 4
// 596.398 us; speedup vs baseline: 5.3485x; 1.1043x over previous
//
#include <hip/hip_runtime.h>
#include <math.h>

#define N_NODES 100000
#define N_EDGES 1600000
#define TWO_E   (2 * N_EDGES)
#define DIM 64
#define SCAN_BLOCKS 98  // ceil(100000/1024)

// ex = exp(sigmoid(as+ad)) — same formula everywhere so denom contributions
// bit-match the per-edge numerators.
__device__ __forceinline__ float edge_ex(float as, float ad) {
    float x = as + ad;
    float sg = 1.0f / (1.0f + __expf(-x));
    return __expf(sg);
}

// K1: per-node attention projections. One wave per node, lane d owns dim d.
__global__ __launch_bounds__(256) void att_kernel(const float* __restrict__ q,
                                                  const float* __restrict__ W_att,
                                                  float* __restrict__ att_src,
                                                  float* __restrict__ att_dst) {
    int wave = (blockIdx.x * blockDim.x + threadIdx.x) >> 6;
    int lane = threadIdx.x & 63;
    if (wave >= N_NODES) return;
    float qv = q[wave * DIM + lane];
    float ps = qv * W_att[lane];
    float pd = qv * W_att[DIM + lane];
    #pragma unroll
    for (int off = 32; off >= 1; off >>= 1) {
        ps += __shfl_xor(ps, off);
        pd += __shfl_xor(pd, off);
    }
    if (lane == 0) {
        att_src[wave] = ps;
        att_dst[wave] = pd;
    }
}

// K2: histogram by dst over both edge types; returned old count = rank in bucket.
__global__ __launch_bounds__(256) void hist_kernel(const int* __restrict__ dst1,
                                                   const int* __restrict__ dst2,
                                                   int* __restrict__ count,
                                                   int* __restrict__ rank) {
    int idx = blockIdx.x * blockDim.x + threadIdx.x;
    if (idx >= TWO_E) return;
    int d = (idx < N_EDGES) ? dst1[idx] : dst2[idx - N_EDGES];
    rank[idx] = atomicAdd(count + d, 1);
}

// K3a: per-block exclusive scan of count -> offsets (block-local), block sums.
__global__ __launch_bounds__(1024) void scan1_kernel(const int* __restrict__ count,
                                                     int* __restrict__ offsets,
                                                     int* __restrict__ bsum) {
    __shared__ int wtot[16];
    int i = blockIdx.x * 1024 + threadIdx.x;
    int v = (i < N_NODES) ? count[i] : 0;
    int lane = threadIdx.x & 63, wid = threadIdx.x >> 6;
    int x = v;
    #pragma unroll
    for (int off = 1; off <= 32; off <<= 1) {
        int y = __shfl_up(x, off);
        if (lane >= off) x += y;
    }
    if (lane == 63) wtot[wid] = x;
    __syncthreads();
    if (threadIdx.x < 16) {
        int t = wtot[threadIdx.x];
        #pragma unroll
        for (int off = 1; off <= 8; off <<= 1) {
            int y = __shfl_up(t, off);
            if (threadIdx.x >= off) t += y;
        }
        wtot[threadIdx.x] = t;  // inclusive scan of wave totals
    }
    __syncthreads();
    int woff = (wid == 0) ? 0 : wtot[wid - 1];
    if (i < N_NODES) offsets[i] = woff + x - v;  // exclusive within block
    if (threadIdx.x == 0) bsum[blockIdx.x] = wtot[15];
}

// K3b: scan the 98 block sums (tiny, single block).
__global__ __launch_bounds__(128) void scan2_kernel(const int* __restrict__ bsum,
                                                    int* __restrict__ boff) {
    __shared__ int s[SCAN_BLOCKS];
    if (threadIdx.x < SCAN_BLOCKS) s[threadIdx.x] = bsum[threadIdx.x];
    __syncthreads();
    if (threadIdx.x == 0) {
        int run = 0;
        for (int b = 0; b < SCAN_BLOCKS; ++b) { int t = s[b]; s[b] = run; run += t; }
    }
    __syncthreads();
    if (threadIdx.x < SCAN_BLOCKS) boff[threadIdx.x] = s[threadIdx.x];
}

// K3c: add block offsets; write the sentinel.
__global__ __launch_bounds__(1024) void scan3_kernel(int* __restrict__ offsets,
                                                     const int* __restrict__ boff) {
    int i = blockIdx.x * 1024 + threadIdx.x;
    if (i < N_NODES) offsets[i] += boff[blockIdx.x];
    if (i == N_NODES - 1) offsets[N_NODES] = TWO_E;
}

// K4: scatter edge records into CSR buckets — NO atomics (pos = offset + rank).
// Record: {src | type<<31, ex as bits}.
__global__ __launch_bounds__(256) void scatter_kernel(const int* __restrict__ src1, const int* __restrict__ dst1,
                                                      const int* __restrict__ src2, const int* __restrict__ dst2,
                                                      const float* __restrict__ att_src, const float* __restrict__ att_dst,
                                                      const int* __restrict__ offsets, const int* __restrict__ rank,
                                                      uint2* __restrict__ recs) {
    int idx = blockIdx.x * blockDim.x + threadIdx.x;
    if (idx >= TWO_E) return;
    int s, d; unsigned tb;
    if (idx < N_EDGES) { s = src1[idx]; d = dst1[idx]; tb = 0u; }
    else               { s = src2[idx - N_EDGES]; d = dst2[idx - N_EDGES]; tb = 0x80000000u; }
    float ex = edge_ex(att_src[s], att_dst[d]);
    int pos = offsets[d] + rank[idx];
    recs[pos] = make_uint2((unsigned)s | tb, __float_as_uint(ex));
}

// K5: gather-reduce per node. 16 threads/node, each owns a float4 chunk.
// Sweep 1: per-type denominators (in-register, shfl reduce).
// Sweep 2: S[n] += (ex/denom) * q[src], one plain float4 store at the end.
__global__ __launch_bounds__(256) void gather_kernel(const float* __restrict__ q,
                                                     const int* __restrict__ offsets,
                                                     const uint2* __restrict__ recs,
                                                     float* __restrict__ S,
                                                     float* __restrict__ fbuf) {
    int node = blockIdx.x * 16 + (threadIdx.x >> 4);
    int t = threadIdx.x & 15;
    if (node >= N_NODES) return;
    int beg = offsets[node], end = offsets[node + 1];
    float d1 = 0.f, d2 = 0.f;
    for (int i = beg + t; i < end; i += 16) {
        uint2 r = recs[i];
        float ex = __uint_as_float(r.y);
        if ((int)r.x < 0) d2 += ex; else d1 += ex;
    }
    #pragma unroll
    for (int off = 8; off >= 1; off >>= 1) {
        d1 += __shfl_xor(d1, off);
        d2 += __shfl_xor(d2, off);
    }
    float inv1 = (d1 > 0.f) ? (1.0f / d1) : 0.f;
    float inv2 = (d2 > 0.f) ? (1.0f / d2) : 0.f;
    if (t == 0) fbuf[node] = ((d1 > 0.f) ? 1.f : 0.f) + ((d2 > 0.f) ? 1.f : 0.f);

    float4 acc = make_float4(0.f, 0.f, 0.f, 0.f);
    const float* qb = q + t * 4;
    int i = beg;
    for (; i + 1 < end; i += 2) {  // unroll x2 for memory-level parallelism
        uint2 r0 = recs[i], r1 = recs[i + 1];
        int s0 = r0.x & 0x7fffffff, s1 = r1.x & 0x7fffffff;
        float a0 = __uint_as_float(r0.y) * (((int)r0.x < 0) ? inv2 : inv1);
        float a1 = __uint_as_float(r1.y) * (((int)r1.x < 0) ? inv2 : inv1);
        const float4 q0 = *reinterpret_cast<const float4*>(qb + (size_t)s0 * DIM);
        const float4 q1 = *reinterpret_cast<const float4*>(qb + (size_t)s1 * DIM);
        acc.x += a0 * q0.x; acc.y += a0 * q0.y; acc.z += a0 * q0.z; acc.w += a0 * q0.w;
        acc.x += a1 * q1.x; acc.y += a1 * q1.y; acc.z += a1 * q1.z; acc.w += a1 * q1.w;
    }
    if (i < end) {
        uint2 r = recs[i];
        int s = r.x & 0x7fffffff;
        float a = __uint_as_float(r.y) * (((int)r.x < 0) ? inv2 : inv1);
        const float4 qv = *reinterpret_cast<const float4*>(qb + (size_t)s * DIM);
        acc.x += a * qv.x; acc.y += a * qv.y; acc.z += a * qv.z; acc.w += a * qv.w;
    }
    *reinterpret_cast<float4*>(S + (size_t)node * DIM + t * 4) = acc;
}

// K6: per-node epilogue, scalar-pipe version. One LANE per node; the node's
// 64-float row lives in VGPRs (all indices compile-time -> registers), W rows
// are wave-uniform -> compiler emits s_load + v_fmac(sgpr, vgpr). Zero LDS ops.
// Pass 1: OV = S @ W_V.T + f*b_V (overwrites S). Pass 2: q_new = (2q+S) @ W_upd.T.
__global__ __launch_bounds__(256) void final_kernel(const float* __restrict__ q,
                                                    const float* __restrict__ W_upd,
                                                    const float* __restrict__ W_V,
                                                    const float* __restrict__ b_V,
                                                    const float* __restrict__ fbuf,
                                                    float* __restrict__ q_new,
                                                    float* S_and_OV) {
    int n = blockIdx.x * 256 + threadIdx.x;
    if (n >= N_NODES) return;
    float r[DIM];
    // Load this node's S row (own row only -> no cross-thread hazard with the
    // in-place OV write below).
    #pragma unroll
    for (int k = 0; k < 16; ++k) {
        float4 v = *reinterpret_cast<const float4*>(S_and_OV + (size_t)n * DIM + k * 4);
        r[4 * k + 0] = v.x; r[4 * k + 1] = v.y; r[4 * k + 2] = v.z; r[4 * k + 3] = v.w;
    }
    float f = fbuf[n];

    // ---- OV = r @ W_V.T + f * b_V ----
    #pragma unroll 1
    for (int c = 0; c < 4; ++c) {           // 4 chunks of 16 output dims
        float acc[16];
        #pragma unroll
        for (int j = 0; j < 16; ++j) acc[j] = f * b_V[c * 16 + j];
        #pragma unroll
        for (int j = 0; j < 16; ++j) {
            const float* wr = W_V + (c * 16 + j) * DIM;  // wave-uniform row
            float a = acc[j];
            #pragma unroll
            for (int d = 0; d < DIM; ++d) a += r[d] * wr[d];
            acc[j] = a;
        }
        float* outp = S_and_OV + (size_t)n * DIM + c * 16;
        #pragma unroll
        for (int k = 0; k < 4; ++k)
            *reinterpret_cast<float4*>(outp + 4 * k) =
                make_float4(acc[4 * k], acc[4 * k + 1], acc[4 * k + 2], acc[4 * k + 3]);
    }

    // ---- u = 2q + S (in place), then q_new = u @ W_upd.T ----
    #pragma unroll
    for (int k = 0; k < 16; ++k) {
        float4 v = *reinterpret_cast<const float4*>(q + (size_t)n * DIM + k * 4);
        r[4 * k + 0] = 2.f * v.x + r[4 * k + 0];
        r[4 * k + 1] = 2.f * v.y + r[4 * k + 1];
        r[4 * k + 2] = 2.f * v.z + r[4 * k + 2];
        r[4 * k + 3] = 2.f * v.w + r[4 * k + 3];
    }
    #pragma unroll 1
    for (int c = 0; c < 4; ++c) {
        float acc[16];
        #pragma unroll
        for (int j = 0; j < 16; ++j) acc[j] = 0.f;
        #pragma unroll
        for (int j = 0; j < 16; ++j) {
            const float* wr = W_upd + (c * 16 + j) * DIM;  // wave-uniform row
            float a = acc[j];
            #pragma unroll
            for (int d = 0; d < DIM; ++d) a += r[d] * wr[d];
            acc[j] = a;
        }
        float* outp = q_new + (size_t)n * DIM + c * 16;
        #pragma unroll
        for (int k = 0; k < 4; ++k)
            *reinterpret_cast<float4*>(outp + 4 * k) =
                make_float4(acc[4 * k], acc[4 * k + 1], acc[4 * k + 2], acc[4 * k + 3]);
    }
}

extern "C" void kernel_launch(void* const* d_in, const int* in_sizes, int n_in,
                              void* d_out, int out_size, void* d_ws, size_t ws_size,
                              hipStream_t stream) {
    const float* q     = (const float*)d_in[0];
    const float* W_att = (const float*)d_in[1];
    const float* W_upd = (const float*)d_in[2];
    const float* W_V   = (const float*)d_in[3];
    const float* b_V   = (const float*)d_in[4];
    const int*   src1  = (const int*)d_in[5];
    const int*   dst1  = (const int*)d_in[6];
    const int*   src2  = (const int*)d_in[7];
    const int*   dst2  = (const int*)d_in[8];

    float* out   = (float*)d_out;
    float* q_new = out;                              // [N,64] final; holds recs until then
    float* S     = out + (size_t)N_NODES * DIM;      // [N,64]: S, then OV in-place
    uint2* recs  = (uint2*)q_new;                    // 2E * 8B == N*DIM*4B exactly

    float* att_src = (float*)d_ws;                   // N
    float* att_dst = att_src + N_NODES;              // N
    float* fbuf    = att_dst + N_NODES;              // N
    int*   count   = (int*)(fbuf + N_NODES);         // N
    int*   offsets = count + N_NODES;                // N+1
    int*   bsum    = offsets + N_NODES + 1;          // 128
    int*   boff    = bsum + 128;                     // 128
    int*   rank    = boff + 128;                     // 2E

    hipMemsetAsync(count, 0, (size_t)N_NODES * sizeof(int), stream);

    att_kernel<<<N_NODES / 4, 256, 0, stream>>>(q, W_att, att_src, att_dst);
    hist_kernel<<<(TWO_E + 255) / 256, 256, 0, stream>>>(dst1, dst2, count, rank);
    scan1_kernel<<<SCAN_BLOCKS, 1024, 0, stream>>>(count, offsets, bsum);
    scan2_kernel<<<1, 128, 0, stream>>>(bsum, boff);
    scan3_kernel<<<SCAN_BLOCKS, 1024, 0, stream>>>(offsets, boff);
    scatter_kernel<<<(TWO_E + 255) / 256, 256, 0, stream>>>(
        src1, dst1, src2, dst2, att_src, att_dst, offsets, rank, recs);
    gather_kernel<<<(N_NODES + 15) / 16, 256, 0, stream>>>(q, offsets, recs, S, fbuf);
    final_kernel<<<(N_NODES + 255) / 256, 256, 0, stream>>>(
        q, W_upd, W_V, b_V, fbuf, q_new, S);
}

// Round 5
// 577.202 us; speedup vs baseline: 5.5264x; 1.0333x over previous
//
#include <hip/hip_runtime.h>
#include <math.h>

#define N_NODES 100000
#define N_EDGES 1600000
#define TWO_E   (2 * N_EDGES)
#define DIM 64
#define SCAN_BLOCKS 98  // ceil(100000/1024)

// ex = exp(sigmoid(as+ad)) — same formula everywhere so denom contributions
// bit-match the per-edge numerators.
__device__ __forceinline__ float edge_ex(float as, float ad) {
    float x = as + ad;
    float sg = 1.0f / (1.0f + __expf(-x));
    return __expf(sg);
}

// K1: per-node attention projections. One wave per node, lane d owns dim d.
__global__ __launch_bounds__(256) void att_kernel(const float* __restrict__ q,
                                                  const float* __restrict__ W_att,
                                                  float* __restrict__ att_src,
                                                  float* __restrict__ att_dst) {
    int wave = (blockIdx.x * blockDim.x + threadIdx.x) >> 6;
    int lane = threadIdx.x & 63;
    if (wave >= N_NODES) return;
    float qv = q[wave * DIM + lane];
    float ps = qv * W_att[lane];
    float pd = qv * W_att[DIM + lane];
    #pragma unroll
    for (int off = 32; off >= 1; off >>= 1) {
        ps += __shfl_xor(ps, off);
        pd += __shfl_xor(pd, off);
    }
    if (lane == 0) {
        att_src[wave] = ps;
        att_dst[wave] = pd;
    }
}

// K2: histogram by dst over both edge types; returned old count = rank in bucket.
__global__ __launch_bounds__(256) void hist_kernel(const int* __restrict__ dst1,
                                                   const int* __restrict__ dst2,
                                                   int* __restrict__ count,
                                                   int* __restrict__ rank) {
    int idx = blockIdx.x * blockDim.x + threadIdx.x;
    if (idx >= TWO_E) return;
    int d = (idx < N_EDGES) ? dst1[idx] : dst2[idx - N_EDGES];
    rank[idx] = atomicAdd(count + d, 1);
}

// K3a: per-block exclusive scan of count -> offsets (block-local), block sums.
__global__ __launch_bounds__(1024) void scan1_kernel(const int* __restrict__ count,
                                                     int* __restrict__ offsets,
                                                     int* __restrict__ bsum) {
    __shared__ int wtot[16];
    int i = blockIdx.x * 1024 + threadIdx.x;
    int v = (i < N_NODES) ? count[i] : 0;
    int lane = threadIdx.x & 63, wid = threadIdx.x >> 6;
    int x = v;
    #pragma unroll
    for (int off = 1; off <= 32; off <<= 1) {
        int y = __shfl_up(x, off);
        if (lane >= off) x += y;
    }
    if (lane == 63) wtot[wid] = x;
    __syncthreads();
    if (threadIdx.x < 16) {
        int t = wtot[threadIdx.x];
        #pragma unroll
        for (int off = 1; off <= 8; off <<= 1) {
            int y = __shfl_up(t, off);
            if (threadIdx.x >= off) t += y;
        }
        wtot[threadIdx.x] = t;  // inclusive scan of wave totals
    }
    __syncthreads();
    int woff = (wid == 0) ? 0 : wtot[wid - 1];
    if (i < N_NODES) offsets[i] = woff + x - v;  // exclusive within block
    if (threadIdx.x == 0) bsum[blockIdx.x] = wtot[15];
}

// K3b: scan the 98 block sums (tiny, single block).
__global__ __launch_bounds__(128) void scan2_kernel(const int* __restrict__ bsum,
                                                    int* __restrict__ boff) {
    __shared__ int s[SCAN_BLOCKS];
    if (threadIdx.x < SCAN_BLOCKS) s[threadIdx.x] = bsum[threadIdx.x];
    __syncthreads();
    if (threadIdx.x == 0) {
        int run = 0;
        for (int b = 0; b < SCAN_BLOCKS; ++b) { int t = s[b]; s[b] = run; run += t; }
    }
    __syncthreads();
    if (threadIdx.x < SCAN_BLOCKS) boff[threadIdx.x] = s[threadIdx.x];
}

// K3c: add block offsets; write the sentinel.
__global__ __launch_bounds__(1024) void scan3_kernel(int* __restrict__ offsets,
                                                     const int* __restrict__ boff) {
    int i = blockIdx.x * 1024 + threadIdx.x;
    if (i < N_NODES) offsets[i] += boff[blockIdx.x];
    if (i == N_NODES - 1) offsets[N_NODES] = TWO_E;
}

// K4: scatter edge records into CSR buckets — NO atomics (pos = offset + rank).
// Record: {src | type<<31, ex as bits}.
__global__ __launch_bounds__(256) void scatter_kernel(const int* __restrict__ src1, const int* __restrict__ dst1,
                                                      const int* __restrict__ src2, const int* __restrict__ dst2,
                                                      const float* __restrict__ att_src, const float* __restrict__ att_dst,
                                                      const int* __restrict__ offsets, const int* __restrict__ rank,
                                                      uint2* __restrict__ recs) {
    int idx = blockIdx.x * blockDim.x + threadIdx.x;
    if (idx >= TWO_E) return;
    int s, d; unsigned tb;
    if (idx < N_EDGES) { s = src1[idx]; d = dst1[idx]; tb = 0u; }
    else               { s = src2[idx - N_EDGES]; d = dst2[idx - N_EDGES]; tb = 0x80000000u; }
    float ex = edge_ex(att_src[s], att_dst[d]);
    int pos = offsets[d] + rank[idx];
    recs[pos] = make_uint2((unsigned)s | tb, __float_as_uint(ex));
}

// K5: gather-reduce per node. 16 threads/node, each owns a float4 chunk.
// Sweep 1: per-type denominators (in-register, shfl reduce).
// Sweep 2: S[n] += (ex/denom) * q[src], one plain float4 store at the end.
__global__ __launch_bounds__(256) void gather_kernel(const float* __restrict__ q,
                                                     const int* __restrict__ offsets,
                                                     const uint2* __restrict__ recs,
                                                     float* __restrict__ S,
                                                     float* __restrict__ fbuf) {
    int node = blockIdx.x * 16 + (threadIdx.x >> 4);
    int t = threadIdx.x & 15;
    if (node >= N_NODES) return;
    int beg = offsets[node], end = offsets[node + 1];
    float d1 = 0.f, d2 = 0.f;
    for (int i = beg + t; i < end; i += 16) {
        uint2 r = recs[i];
        float ex = __uint_as_float(r.y);
        if ((int)r.x < 0) d2 += ex; else d1 += ex;
    }
    #pragma unroll
    for (int off = 8; off >= 1; off >>= 1) {
        d1 += __shfl_xor(d1, off);
        d2 += __shfl_xor(d2, off);
    }
    float inv1 = (d1 > 0.f) ? (1.0f / d1) : 0.f;
    float inv2 = (d2 > 0.f) ? (1.0f / d2) : 0.f;
    if (t == 0) fbuf[node] = ((d1 > 0.f) ? 1.f : 0.f) + ((d2 > 0.f) ? 1.f : 0.f);

    float4 acc = make_float4(0.f, 0.f, 0.f, 0.f);
    const float* qb = q + t * 4;
    int i = beg;
    for (; i + 1 < end; i += 2) {  // unroll x2 for memory-level parallelism
        uint2 r0 = recs[i], r1 = recs[i + 1];
        int s0 = r0.x & 0x7fffffff, s1 = r1.x & 0x7fffffff;
        float a0 = __uint_as_float(r0.y) * (((int)r0.x < 0) ? inv2 : inv1);
        float a1 = __uint_as_float(r1.y) * (((int)r1.x < 0) ? inv2 : inv1);
        const float4 q0 = *reinterpret_cast<const float4*>(qb + (size_t)s0 * DIM);
        const float4 q1 = *reinterpret_cast<const float4*>(qb + (size_t)s1 * DIM);
        acc.x += a0 * q0.x; acc.y += a0 * q0.y; acc.z += a0 * q0.z; acc.w += a0 * q0.w;
        acc.x += a1 * q1.x; acc.y += a1 * q1.y; acc.z += a1 * q1.z; acc.w += a1 * q1.w;
    }
    if (i < end) {
        uint2 r = recs[i];
        int s = r.x & 0x7fffffff;
        float a = __uint_as_float(r.y) * (((int)r.x < 0) ? inv2 : inv1);
        const float4 qv = *reinterpret_cast<const float4*>(qb + (size_t)s * DIM);
        acc.x += a * qv.x; acc.y += a * qv.y; acc.z += a * qv.z; acc.w += a * qv.w;
    }
    *reinterpret_cast<float4*>(S + (size_t)node * DIM + t * 4) = acc;
}

// K6: per-node epilogue, wave-task version. Block = 512 threads = 8 waves
// covering 64 nodes (lane = node). Each wave owns one (m, c) task:
//   m=0: OV chunk c  = S_row @ W_V[c*16..].T + f*b_V   (overwrites S in place)
//   m=1: q_new chunk c = (2q+S)_row @ W_upd[c*16..].T
// m,c go through readfirstlane -> SGPR, so every weight address is provably
// wave-uniform -> s_load + v_fmac(sgpr, vgpr). __syncthreads separates all
// S-reads from the in-place OV overwrite.
__global__ __launch_bounds__(512) void final_kernel(const float* __restrict__ q,
                                                    const float* __restrict__ W_upd,
                                                    const float* __restrict__ W_V,
                                                    const float* __restrict__ b_V,
                                                    const float* __restrict__ fbuf,
                                                    float* __restrict__ q_new,
                                                    float* S_and_OV) {
    int lane = threadIdx.x & 63;
    int w = threadIdx.x >> 6;                               // 0..7
    int ms = __builtin_amdgcn_readfirstlane(w >> 2);        // 0: OV, 1: q_new
    int cs = __builtin_amdgcn_readfirstlane(w & 3);         // output chunk
    int node = blockIdx.x * 64 + lane;
    bool active = node < N_NODES;

    float r[DIM];
    float f = 0.f;
    if (active) {
        const float* srow = S_and_OV + (size_t)node * DIM;
        if (ms == 0) {
            #pragma unroll
            for (int k = 0; k < 16; ++k) {
                float4 v = *reinterpret_cast<const float4*>(srow + 4 * k);
                r[4 * k + 0] = v.x; r[4 * k + 1] = v.y;
                r[4 * k + 2] = v.z; r[4 * k + 3] = v.w;
            }
            f = fbuf[node];
        } else {
            const float* qrow = q + (size_t)node * DIM;
            #pragma unroll
            for (int k = 0; k < 16; ++k) {
                float4 sv = *reinterpret_cast<const float4*>(srow + 4 * k);
                float4 qv = *reinterpret_cast<const float4*>(qrow + 4 * k);
                r[4 * k + 0] = 2.f * qv.x + sv.x;
                r[4 * k + 1] = 2.f * qv.y + sv.y;
                r[4 * k + 2] = 2.f * qv.z + sv.z;
                r[4 * k + 3] = 2.f * qv.w + sv.w;
            }
        }
    } else {
        #pragma unroll
        for (int d = 0; d < DIM; ++d) r[d] = 0.f;
    }

    __syncthreads();  // all S reads done before OV overwrites S

    const float* Wbase = ms ? W_upd : W_V;
    float acc[16];
    #pragma unroll
    for (int j = 0; j < 16; ++j) acc[j] = (ms == 0) ? f * b_V[cs * 16 + j] : 0.f;
    #pragma unroll
    for (int j = 0; j < 16; ++j) {
        const float* wr = Wbase + (cs * 16 + j) * DIM;  // wave-uniform -> s_load
        float a = acc[j];
        #pragma unroll
        for (int d = 0; d < DIM; ++d) a += r[d] * wr[d];
        acc[j] = a;
    }

    if (active) {
        float* outp = (ms ? q_new : S_and_OV) + (size_t)node * DIM + cs * 16;
        #pragma unroll
        for (int k = 0; k < 4; ++k)
            *reinterpret_cast<float4*>(outp + 4 * k) =
                make_float4(acc[4 * k], acc[4 * k + 1], acc[4 * k + 2], acc[4 * k + 3]);
    }
}

extern "C" void kernel_launch(void* const* d_in, const int* in_sizes, int n_in,
                              void* d_out, int out_size, void* d_ws, size_t ws_size,
                              hipStream_t stream) {
    const float* q     = (const float*)d_in[0];
    const float* W_att = (const float*)d_in[1];
    const float* W_upd = (const float*)d_in[2];
    const float* W_V   = (const float*)d_in[3];
    const float* b_V   = (const float*)d_in[4];
    const int*   src1  = (const int*)d_in[5];
    const int*   dst1  = (const int*)d_in[6];
    const int*   src2  = (const int*)d_in[7];
    const int*   dst2  = (const int*)d_in[8];

    float* out   = (float*)d_out;
    float* q_new = out;                              // [N,64] final; holds recs until then
    float* S     = out + (size_t)N_NODES * DIM;      // [N,64]: S, then OV in-place
    uint2* recs  = (uint2*)q_new;                    // 2E * 8B == N*DIM*4B exactly

    float* att_src = (float*)d_ws;                   // N
    float* att_dst = att_src + N_NODES;              // N
    float* fbuf    = att_dst + N_NODES;              // N
    int*   count   = (int*)(fbuf + N_NODES);         // N
    int*   offsets = count + N_NODES;                // N+1
    int*   bsum    = offsets + N_NODES + 1;          // 128
    int*   boff    = bsum + 128;                     // 128
    int*   rank    = boff + 128;                     // 2E

    hipMemsetAsync(count, 0, (size_t)N_NODES * sizeof(int), stream);

    att_kernel<<<N_NODES / 4, 256, 0, stream>>>(q, W_att, att_src, att_dst);
    hist_kernel<<<(TWO_E + 255) / 256, 256, 0, stream>>>(dst1, dst2, count, rank);
    scan1_kernel<<<SCAN_BLOCKS, 1024, 0, stream>>>(count, offsets, bsum);
    scan2_kernel<<<1, 128, 0, stream>>>(bsum, boff);
    scan3_kernel<<<SCAN_BLOCKS, 1024, 0, stream>>>(offsets, boff);
    scatter_kernel<<<(TWO_E + 255) / 256, 256, 0, stream>>>(
        src1, dst1, src2, dst2, att_src, att_dst, offsets, rank, recs);
    gather_kernel<<<(N_NODES + 15) / 16, 256, 0, stream>>>(q, offsets, recs, S, fbuf);
    final_kernel<<<(N_NODES + 63) / 64, 512, 0, stream>>>(
        q, W_upd, W_V, b_V, fbuf, q_new, S);
}